// Round 26
// baseline (53.567 us; speedup 1.0000x reference)
//
#include <hip/hip_runtime.h>
#include <math.h>

namespace {
constexpr int   NB   = 25;     // basis functions
constexpr int   TS   = 301;    // time steps
constexpr int   NTT  = 19;     // t-tiles of 16 (304)
constexpr float DT   = 0.01f;
constexpr float TAU  = 3.0f;
constexpr float AX   = 2.0f;
constexpr float AZ   = 48.0f;
constexpr float BZ   = 12.0f;  // AZ/4
constexpr int   BATCH = 65536;

typedef float  f32x4  __attribute__((ext_vector_type(4)));
typedef float  f32x4u __attribute__((ext_vector_type(4), aligned(4)));
typedef short  s16x8  __attribute__((ext_vector_type(8)));

__device__ inline ushort f2bf(float f) {           // RNE float->bf16
  uint u = __float_as_uint(f);
  uint r = u + 0x7fffu + ((u >> 16) & 1u);
  return (ushort)(r >> 16);
}
__device__ inline float bf2f(ushort h) {
  return __uint_as_float(((uint)h) << 16);
}
__device__ inline void mat3mul(float* R, const float* S) {  // R = R*S
  float T[9];
  #pragma unroll
  for (int i = 0; i < 3; ++i)
    #pragma unroll
    for (int j = 0; j < 3; ++j)
      T[3*i+j] = R[3*i+0]*S[0+j] + R[3*i+1]*S[3+j] + R[3*i+2]*S[6+j];
  #pragma unroll
  for (int i = 0; i < 9; ++i) R[i] = T[i];
}
}

// ws layout (ushort8 records of 16B):
//   hi table: record[(d*NTT + tt)*64 + lane], 2432 records
//   lo table: follows at +2432 records.                 total 77,824 B
// Distributed precompute (R22-proven, -25us): 19 independent blocks, one
// per 16-t chunk, closed-form P_k=[N^k]01 via binary exponentiation.
__global__ __launch_bounds__(512)
void dmp_precompute(const float* __restrict__ c, const float* __restrict__ s2,
                    const float* __restrict__ scale, ushort* __restrict__ ws2) {
  __shared__ float gT[NB][304];        // basis columns j <= t0+15 used
  __shared__ float part[NB][NTT][16];  // conv partials
  __shared__ float Hc[NB + 2][16];     // this chunk: [0]=A,[1]=B,[2+n]=H_n
  __shared__ float Pbuf[320];          // Pext = Pbuf+16; [0..15] = 0 pad
  __shared__ float cS[NB], vS[NB];
  const int tid = threadIdx.x;
  const int tt  = blockIdx.x;          // 0..18
  const int t0  = tt * 16;
  if (tid < NB) { cS[tid] = c[tid]; vS[tid] = s2[tid]; }
  if (tid < 16) Pbuf[tid] = 0.f;                       // negative-index pad
  if (tid >= 301 && tid < 304) Pbuf[16 + tid] = 0.f;   // tail pad
  __syncthreads();

  // ---- phase 1: basis table gT[n][j] ----
  const float q = 1.0f - AX / TAU * DT;   // cx multiplier per step
  for (int i = tid; i < 304; i += 512) {
    if (i < TS) {
      float cx = powf(q, (float)(i + 1));   // cx updated BEFORE use in ref
      float p[NB]; float sum = 0.f;
      #pragma unroll
      for (int n = 0; n < NB; ++n) {
        float d = cx - cS[n];
        p[n] = expf(-0.5f * d * d / vS[n]);
        sum += p[n];
      }
      float m = cx / sum;
      #pragma unroll
      for (int n = 0; n < NB; ++n) gT[n][i] = p[n] * m;
    } else {
      #pragma unroll
      for (int n = 0; n < NB; ++n) gT[n][i] = 0.f;
    }
  }

  // ---- phase 2: N^k closed form; P[k], and A/B for this chunk ----
  if (tid < 302) {
    const float a01 = DT / TAU;
    const float a10 = -AZ * BZ * DT / TAU;
    const float a11 = 1.0f - AZ * DT / TAU;
    const float b1  = AZ * BZ * DT / TAU;
    float Npow[9][9];                        // Npow[i] = N^(2^i)
    Npow[0][0]=1.f;  Npow[0][1]=a01; Npow[0][2]=0.f;
    Npow[0][3]=a10;  Npow[0][4]=a11; Npow[0][5]=b1;
    Npow[0][6]=0.f;  Npow[0][7]=0.f; Npow[0][8]=1.f;
    #pragma unroll
    for (int i = 1; i < 9; ++i) {
      #pragma unroll
      for (int e = 0; e < 9; ++e) Npow[i][e] = Npow[i - 1][e];
      mat3mul(Npow[i], Npow[i - 1]);
    }
    float R[9] = {1.f,0.f,0.f, 0.f,1.f,0.f, 0.f,0.f,1.f};
    #pragma unroll
    for (int i = 0; i < 9; ++i)
      if ((tid >> i) & 1) mat3mul(R, Npow[i]);
    if (tid <= 300) Pbuf[16 + tid] = R[1];   // P_k = [N^k]01
    const int t = tid - 1;                   // A_t,B_t from N^{t+1}
    if (t >= t0 && t < t0 + 16) {
      Hc[0][t - t0] = R[0];                  // A_t
      Hc[1][t - t0] = R[2];                  // B_t
    }
  }
  __syncthreads();

  // ---- phase 3: conv partials, then per-n reduce (ascending jb) ----
  {
    const int ntasks = NB * (tt + 1);
    if (tid < ntasks) {
      const int n   = tid / (tt + 1);
      const int jbi = tid - n * (tt + 1);
      const int jb  = jbi * 16;
      const float* __restrict__ Pext = Pbuf + 16;
      float acc[16];
      #pragma unroll
      for (int i = 0; i < 16; ++i) acc[i] = 0.f;
      float gv[16], pv[31];
      #pragma unroll
      for (int jj = 0; jj < 16; ++jj) gv[jj] = gT[n][jb + jj];
      #pragma unroll
      for (int k = 0; k < 31; ++k) pv[k] = Pext[t0 - jb - 15 + k];
      #pragma unroll
      for (int i = 0; i < 16; ++i)
        #pragma unroll
        for (int jj = 0; jj < 16; ++jj)
          acc[i] = fmaf(gv[jj], pv[15 + i - jj], acc[i]);
      #pragma unroll
      for (int i = 0; i < 16; ++i) part[n][jbi][i] = acc[i];
    }
  }
  __syncthreads();
  if (tid < NB) {
    const float sc_ = DT / TAU;
    float acc[16];
    #pragma unroll
    for (int i = 0; i < 16; ++i) acc[i] = 0.f;
    for (int jbi = 0; jbi <= tt; ++jbi)
      #pragma unroll
      for (int i = 0; i < 16; ++i) acc[i] += part[tid][jbi][i];
    #pragma unroll
    for (int i = 0; i < 16; ++i) Hc[2 + tid][i] = acc[i] * sc_;
  }
  __syncthreads();

  // ---- phase 4: emit this chunk's 128 hi/lo records ----
  constexpr int NREC = 2 * NTT * 64;   // 2432
  if (tid < 128) {
    const int d    = tid >> 6;
    const int lane = tid & 63;
    const int kb   = (lane >> 4) * 8;
    const int tl   = lane & 15;
    const int t    = t0 + tl;
    const int rec  = (d * NTT + tt) * 64 + lane;
    ushort* dst_h = ws2 + (size_t)rec * 8;
    ushort* dst_l = ws2 + (size_t)(NREC + rec) * 8;
    #pragma unroll
    for (int j = 0; j < 8; ++j) {
      const int k = kb + j;
      float v = 0.f;
      if (t < TS) {
        if (k == 5)                 v = Hc[0][tl];
        else if (k == 6)            v = Hc[1][tl];
        else if (k >= 7 && k <= 31) v = Hc[2 + (k - 7)][tl] * scale[d * 27 + 2 + (k - 7)];
      }
      const ushort h = f2bf(v);
      dst_h[j] = h;
      dst_l[j] = f2bf(v - bf2f(h));
    }
  }
}

// MFMA GEMM, math == R14/R18 (validated absmax 0.031). Structure == R22's
// 51.9us kernel with ONE lever: t-split generation pipelining. R25 showed
// grid(2048) == exact residency at 8 blocks/CU -> all blocks phase-locked:
// the x-stage+barrier+frag prefix runs chip-wide with zero stores in
// flight, and store ramp/drain has no other generation to overlap with.
// Now each block does ONE T-HALF (tt 0..9 or 10..18): 4096 blocks, 2048
// resident -> two generations; gen-2's prefix overlaps gen-1's drain.
// Second x read is L3-hit (14 MB << 256 MB). Half boundary = byte 640 of
// each row = sector-aligned (640 = 10*64): no new partial sectors.
__global__ __launch_bounds__(256, 8)
void dmp_mfma(const float* __restrict__ x, const float* __restrict__ scale,
              const ushort* __restrict__ ws2, float* __restrict__ out) {
  __shared__ float sh[1728];                 // 64 rows x 27 floats
  const int tid  = threadIdx.x;
  const int w    = tid >> 6;
  const int lane = tid & 63;
  const int d    = w & 1;
  const int pg   = w >> 1;
  const int bp   = blockIdx.x >> 1;          // pair-group-of-32 index
  const int th   = blockIdx.x & 1;           // t-half
  const int rowb = bp * 32 + pg * 16;        // 16 batch-pairs
  const int m    = lane & 15;
  const int g    = lane >> 4;

  // ---- coalesced stage: block's 64 rows of x -> LDS ----
  {
    const float* __restrict__ xsrc = x + (size_t)bp * 1728;
    #pragma unroll
    for (int it = 0; it < 7; ++it) {
      const int idx = it * 256 + tid;
      if (idx < 1728) sh[idx] = xsrc[idx];
    }
  }
  __syncthreads();

  // ---- build x fragment (hi/lo) from LDS ----
  const float* __restrict__ xr = sh + (2 * (pg * 16 + m) + d) * 27;
  const float y0s = xr[0] * scale[d * 27];
  const float gs  = xr[1] * scale[d * 27 + 1];
  const float dd  = gs - y0s;
  s16x8 Xh, Xl;
  #pragma unroll
  for (int j = 0; j < 8; ++j) {
    const int k   = 8 * g + j;
    const int idx = (k >= 7) ? (k - 5) : 0;      // clamp: no OOB
    const float wv = xr[idx] * dd;
    const float e  = (k < 5) ? 0.f : (k == 5) ? y0s : (k == 6) ? gs : wv;
    const ushort h = f2bf(e);
    Xh[j] = (short)h;
    Xl[j] = (short)f2bf(e - bf2f(h));
  }

  constexpr int NREC = 2 * NTT * 64;
  const s16x8* __restrict__ Th =
      (const s16x8*)ws2 + (size_t)(d * NTT) * 64 + lane;
  const s16x8* __restrict__ Tl = Th + NREC;

  float* __restrict__ orow = out + (size_t)(2 * (rowb + m) + d) * TS;

  if (th == 0) {
    #pragma unroll
    for (int tt = 0; tt < 10; ++tt) {
      const s16x8 thv = Th[tt * 64];
      const s16x8 tlv = Tl[tt * 64];
      f32x4 acc = {0.f, 0.f, 0.f, 0.f};
      acc = __builtin_amdgcn_mfma_f32_16x16x32_bf16(thv, Xh, acc, 0, 0, 0);
      acc = __builtin_amdgcn_mfma_f32_16x16x32_bf16(tlv, Xh, acc, 0, 0, 0);
      acc = __builtin_amdgcn_mfma_f32_16x16x32_bf16(thv, Xl, acc, 0, 0, 0);
      *(f32x4u*)(orow + tt * 16 + 4 * g) = acc;
    }
  } else {
    #pragma unroll
    for (int tt = 10; tt < NTT; ++tt) {
      const s16x8 thv = Th[tt * 64];
      const s16x8 tlv = Tl[tt * 64];
      f32x4 acc = {0.f, 0.f, 0.f, 0.f};
      acc = __builtin_amdgcn_mfma_f32_16x16x32_bf16(thv, Xh, acc, 0, 0, 0);
      acc = __builtin_amdgcn_mfma_f32_16x16x32_bf16(tlv, Xh, acc, 0, 0, 0);
      acc = __builtin_amdgcn_mfma_f32_16x16x32_bf16(thv, Xl, acc, 0, 0, 0);
      const int t0 = tt * 16 + 4 * g;
      if (tt < NTT - 1) {
        *(f32x4u*)(orow + t0) = acc;
      } else {
        if (g < 3)       *(f32x4u*)(orow + t0) = acc;
        else if (t0 < TS) orow[t0] = acc[0];       // t = 300 only
      }
    }
  }
}

extern "C" void kernel_launch(void* const* d_in, const int* in_sizes, int n_in,
                              void* d_out, int out_size, void* d_ws, size_t ws_size,
                              hipStream_t stream) {
  const float* x  = (const float*)d_in[0];
  const float* c  = (const float*)d_in[1];
  const float* s2 = (const float*)d_in[2];
  const float* sc = (const float*)d_in[3];
  ushort* ws2 = (ushort*)d_ws;   // needs 77,824 bytes
  float* out = (float*)d_out;

  hipLaunchKernelGGL(dmp_precompute, dim3(NTT), dim3(512), 0, stream,
                     c, s2, sc, ws2);
  hipLaunchKernelGGL(dmp_mfma, dim3((BATCH / 32) * 2), dim3(256), 0, stream,
                     x, sc, ws2, out);
}

// Round 27
// 51.793 us; speedup vs baseline: 1.0343x; 1.0343x over previous
//
#include <hip/hip_runtime.h>
#include <math.h>

namespace {
constexpr int   NB   = 25;     // basis functions
constexpr int   TS   = 301;    // time steps
constexpr int   NTT  = 19;     // t-tiles of 16 (304)
constexpr float DT   = 0.01f;
constexpr float TAU  = 3.0f;
constexpr float AX   = 2.0f;
constexpr float AZ   = 48.0f;
constexpr float BZ   = 12.0f;  // AZ/4
constexpr int   BATCH = 65536;

typedef float  f32x4  __attribute__((ext_vector_type(4)));
typedef float  f32x4u __attribute__((ext_vector_type(4), aligned(4)));
typedef short  s16x8  __attribute__((ext_vector_type(8)));

__device__ inline ushort f2bf(float f) {           // RNE float->bf16
  uint u = __float_as_uint(f);
  uint r = u + 0x7fffu + ((u >> 16) & 1u);
  return (ushort)(r >> 16);
}
__device__ inline float bf2f(ushort h) {
  return __uint_as_float(((uint)h) << 16);
}
__device__ inline void mat3mul(float* R, const float* S) {  // R = R*S
  float T[9];
  #pragma unroll
  for (int i = 0; i < 3; ++i)
    #pragma unroll
    for (int j = 0; j < 3; ++j)
      T[3*i+j] = R[3*i+0]*S[0+j] + R[3*i+1]*S[3+j] + R[3*i+2]*S[6+j];
  #pragma unroll
  for (int i = 0; i < 9; ++i) R[i] = T[i];
}
}

// ws layout (ushort8 records of 16B):
//   hi table: record[(d*NTT + tt)*64 + lane], 2432 records
//   lo table: follows at +2432 records.                 total 77,824 B
// Distributed precompute (R22-proven, -25us): 19 independent blocks, one
// per 16-t chunk, closed-form P_k=[N^k]01 via binary exponentiation.
__global__ __launch_bounds__(512)
void dmp_precompute(const float* __restrict__ c, const float* __restrict__ s2,
                    const float* __restrict__ scale, ushort* __restrict__ ws2) {
  __shared__ float gT[NB][304];        // basis columns j <= t0+15 used
  __shared__ float part[NB][NTT][16];  // conv partials
  __shared__ float Hc[NB + 2][16];     // this chunk: [0]=A,[1]=B,[2+n]=H_n
  __shared__ float Pbuf[320];          // Pext = Pbuf+16; [0..15] = 0 pad
  __shared__ float cS[NB], vS[NB];
  const int tid = threadIdx.x;
  const int tt  = blockIdx.x;          // 0..18
  const int t0  = tt * 16;
  if (tid < NB) { cS[tid] = c[tid]; vS[tid] = s2[tid]; }
  if (tid < 16) Pbuf[tid] = 0.f;                       // negative-index pad
  if (tid >= 301 && tid < 304) Pbuf[16 + tid] = 0.f;   // tail pad
  __syncthreads();

  // ---- phase 1: basis table gT[n][j] ----
  const float q = 1.0f - AX / TAU * DT;   // cx multiplier per step
  for (int i = tid; i < 304; i += 512) {
    if (i < TS) {
      float cx = powf(q, (float)(i + 1));   // cx updated BEFORE use in ref
      float p[NB]; float sum = 0.f;
      #pragma unroll
      for (int n = 0; n < NB; ++n) {
        float d = cx - cS[n];
        p[n] = expf(-0.5f * d * d / vS[n]);
        sum += p[n];
      }
      float m = cx / sum;
      #pragma unroll
      for (int n = 0; n < NB; ++n) gT[n][i] = p[n] * m;
    } else {
      #pragma unroll
      for (int n = 0; n < NB; ++n) gT[n][i] = 0.f;
    }
  }

  // ---- phase 2: N^k closed form; P[k], and A/B for this chunk ----
  if (tid < 302) {
    const float a01 = DT / TAU;
    const float a10 = -AZ * BZ * DT / TAU;
    const float a11 = 1.0f - AZ * DT / TAU;
    const float b1  = AZ * BZ * DT / TAU;
    float Npow[9][9];                        // Npow[i] = N^(2^i)
    Npow[0][0]=1.f;  Npow[0][1]=a01; Npow[0][2]=0.f;
    Npow[0][3]=a10;  Npow[0][4]=a11; Npow[0][5]=b1;
    Npow[0][6]=0.f;  Npow[0][7]=0.f; Npow[0][8]=1.f;
    #pragma unroll
    for (int i = 1; i < 9; ++i) {
      #pragma unroll
      for (int e = 0; e < 9; ++e) Npow[i][e] = Npow[i - 1][e];
      mat3mul(Npow[i], Npow[i - 1]);
    }
    float R[9] = {1.f,0.f,0.f, 0.f,1.f,0.f, 0.f,0.f,1.f};
    #pragma unroll
    for (int i = 0; i < 9; ++i)
      if ((tid >> i) & 1) mat3mul(R, Npow[i]);
    if (tid <= 300) Pbuf[16 + tid] = R[1];   // P_k = [N^k]01
    const int t = tid - 1;                   // A_t,B_t from N^{t+1}
    if (t >= t0 && t < t0 + 16) {
      Hc[0][t - t0] = R[0];                  // A_t
      Hc[1][t - t0] = R[2];                  // B_t
    }
  }
  __syncthreads();

  // ---- phase 3: conv partials, then per-n reduce (ascending jb) ----
  {
    const int ntasks = NB * (tt + 1);
    if (tid < ntasks) {
      const int n   = tid / (tt + 1);
      const int jbi = tid - n * (tt + 1);
      const int jb  = jbi * 16;
      const float* __restrict__ Pext = Pbuf + 16;
      float acc[16];
      #pragma unroll
      for (int i = 0; i < 16; ++i) acc[i] = 0.f;
      float gv[16], pv[31];
      #pragma unroll
      for (int jj = 0; jj < 16; ++jj) gv[jj] = gT[n][jb + jj];
      #pragma unroll
      for (int k = 0; k < 31; ++k) pv[k] = Pext[t0 - jb - 15 + k];
      #pragma unroll
      for (int i = 0; i < 16; ++i)
        #pragma unroll
        for (int jj = 0; jj < 16; ++jj)
          acc[i] = fmaf(gv[jj], pv[15 + i - jj], acc[i]);
      #pragma unroll
      for (int i = 0; i < 16; ++i) part[n][jbi][i] = acc[i];
    }
  }
  __syncthreads();
  if (tid < NB) {
    const float sc_ = DT / TAU;
    float acc[16];
    #pragma unroll
    for (int i = 0; i < 16; ++i) acc[i] = 0.f;
    for (int jbi = 0; jbi <= tt; ++jbi)
      #pragma unroll
      for (int i = 0; i < 16; ++i) acc[i] += part[tid][jbi][i];
    #pragma unroll
    for (int i = 0; i < 16; ++i) Hc[2 + tid][i] = acc[i] * sc_;
  }
  __syncthreads();

  // ---- phase 4: emit this chunk's 128 hi/lo records ----
  constexpr int NREC = 2 * NTT * 64;   // 2432
  if (tid < 128) {
    const int d    = tid >> 6;
    const int lane = tid & 63;
    const int kb   = (lane >> 4) * 8;
    const int tl   = lane & 15;
    const int t    = t0 + tl;
    const int rec  = (d * NTT + tt) * 64 + lane;
    ushort* dst_h = ws2 + (size_t)rec * 8;
    ushort* dst_l = ws2 + (size_t)(NREC + rec) * 8;
    #pragma unroll
    for (int j = 0; j < 8; ++j) {
      const int k = kb + j;
      float v = 0.f;
      if (t < TS) {
        if (k == 5)                 v = Hc[0][tl];
        else if (k == 6)            v = Hc[1][tl];
        else if (k >= 7 && k <= 31) v = Hc[2 + (k - 7)][tl] * scale[d * 27 + 2 + (k - 7)];
      }
      const ushort h = f2bf(v);
      dst_h[j] = h;
      dst_l[j] = f2bf(v - bf2f(h));
    }
  }
}

// MFMA GEMM, math == R14/R18 (validated absmax 0.031). FINAL configuration
// == R22's best-measured 51.9us kernel, reverted after R23-R26 single-lever
// experiments on the residual ~13us all came back null or negative:
//   R23 nontemporal stores: WRITE 257MB (defeats L2 write-combining) -4x
//   R24 both-dof sector-complete waves: -7us (halved wave count)
//   R25 (256,8) occupancy: null;  R26 t-split generation overlap: null
// Decomposition: ~30us HBM write wall (188MB actual @ ~6.3TB/s incl. the
// 1.19x amp inherent to the 1204B row stride) + ~8-10us single-pass
// ramp/drain residual + ~6us precompute/launch ~= the measured 52us.
__global__ __launch_bounds__(256, 4)
void dmp_mfma(const float* __restrict__ x, const float* __restrict__ scale,
              const ushort* __restrict__ ws2, float* __restrict__ out) {
  __shared__ float sh[1728];                 // 64 rows x 27 floats
  const int tid  = threadIdx.x;
  const int w    = tid >> 6;
  const int lane = tid & 63;
  const int d    = w & 1;
  const int pg   = w >> 1;
  const int rowb = blockIdx.x * 32 + pg * 16;   // 16 batch-pairs
  const int m    = lane & 15;
  const int g    = lane >> 4;

  // ---- coalesced stage: block's 64 rows of x -> LDS ----
  {
    const float* __restrict__ xsrc = x + (size_t)blockIdx.x * 1728;
    #pragma unroll
    for (int it = 0; it < 7; ++it) {
      const int idx = it * 256 + tid;
      if (idx < 1728) sh[idx] = xsrc[idx];
    }
  }
  __syncthreads();

  // ---- build x fragment (hi/lo) from LDS ----
  const float* __restrict__ xr = sh + (2 * (pg * 16 + m) + d) * 27;
  const float y0s = xr[0] * scale[d * 27];
  const float gs  = xr[1] * scale[d * 27 + 1];
  const float dd  = gs - y0s;
  s16x8 Xh, Xl;
  #pragma unroll
  for (int j = 0; j < 8; ++j) {
    const int k   = 8 * g + j;
    const int idx = (k >= 7) ? (k - 5) : 0;      // clamp: no OOB
    const float wv = xr[idx] * dd;
    const float e  = (k < 5) ? 0.f : (k == 5) ? y0s : (k == 6) ? gs : wv;
    const ushort h = f2bf(e);
    Xh[j] = (short)h;
    Xl[j] = (short)f2bf(e - bf2f(h));
  }

  constexpr int NREC = 2 * NTT * 64;
  const s16x8* __restrict__ Th =
      (const s16x8*)ws2 + (size_t)(d * NTT) * 64 + lane;
  const s16x8* __restrict__ Tl = Th + NREC;

  float* __restrict__ orow = out + (size_t)(2 * (rowb + m) + d) * TS;

  #pragma unroll
  for (int tt = 0; tt < NTT; ++tt) {
    const s16x8 th = Th[tt * 64];
    const s16x8 tl = Tl[tt * 64];
    f32x4 acc = {0.f, 0.f, 0.f, 0.f};
    acc = __builtin_amdgcn_mfma_f32_16x16x32_bf16(th, Xh, acc, 0, 0, 0);
    acc = __builtin_amdgcn_mfma_f32_16x16x32_bf16(tl, Xh, acc, 0, 0, 0);
    acc = __builtin_amdgcn_mfma_f32_16x16x32_bf16(th, Xl, acc, 0, 0, 0);
    const int t0 = tt * 16 + 4 * g;
    if (tt < NTT - 1) {
      *(f32x4u*)(orow + t0) = acc;               // 16 B, 4 consecutive t
    } else {
      if (g < 3)       *(f32x4u*)(orow + t0) = acc;
      else if (t0 < TS) orow[t0] = acc[0];       // t = 300 only
    }
  }
}

extern "C" void kernel_launch(void* const* d_in, const int* in_sizes, int n_in,
                              void* d_out, int out_size, void* d_ws, size_t ws_size,
                              hipStream_t stream) {
  const float* x  = (const float*)d_in[0];
  const float* c  = (const float*)d_in[1];
  const float* s2 = (const float*)d_in[2];
  const float* sc = (const float*)d_in[3];
  ushort* ws2 = (ushort*)d_ws;   // needs 77,824 bytes
  float* out = (float*)d_out;

  hipLaunchKernelGGL(dmp_precompute, dim3(NTT), dim3(512), 0, stream,
                     c, s2, sc, ws2);
  hipLaunchKernelGGL(dmp_mfma, dim3(BATCH / 32), dim3(256), 0, stream,
                     x, sc, ws2, out);
}